// Round 3
// baseline (327.474 us; speedup 1.0000x reference)
//
#include <hip/hip_runtime.h>

// Fused SDPA, MI355X gfx950. G=32, H=8, L=512, D=64.
// q:(G,H,L,D) f32, k:(G,H,D,L) f32, v:(G,H,L,D) f32, mask:(8,L,L) int
// (nonzero = masked), out:(G,H,L,D) f32.
//
// Round 3: software-pipelined K-loop. Double-buffered LDS (2x16KB), register
// prefetch of chunk kb+1 (K at iteration top, V mid-iteration), pack+write
// after compute, ONE barrier per iteration. Mask loads hoisted ahead of the
// MFMAs they feed. log2(e) folded into the Q pre-scale so exp is a bare
// v_exp_f32. Everything else (S^T trick, lane-local softmax, register P
// exchange, direct coalesced O stores) as round 2.

typedef __attribute__((ext_vector_type(8)))  short bf16x8;
typedef __attribute__((ext_vector_type(16))) float f32x16;

union Frag4 { uint4 x; unsigned u[4]; bf16x8 v; };

// pack two f32 -> packed bf16 pair (a -> low, b -> high), round-half-up
__device__ __forceinline__ unsigned pk_bf16(float a, float b){
    unsigned ua = __builtin_bit_cast(unsigned, a) + 0x8000u;
    unsigned ub = __builtin_bit_cast(unsigned, b) + 0x8000u;
    return __builtin_amdgcn_perm(ub, ua, 0x07060302u);
}

__device__ __forceinline__ float fast_exp2(float x){
#if __has_builtin(__builtin_amdgcn_exp2f)
    return __builtin_amdgcn_exp2f(x);
#else
    return exp2f(x);
#endif
}

#define SCL 0.1803368801111204f   // 0.125 * log2(e): GEMM1 output is exp2-ready

__global__ __launch_bounds__(256, 4)
void attn_fused(const float* __restrict__ qg, const float* __restrict__ kg,
                const float* __restrict__ vg, const int* __restrict__ mg,
                float* __restrict__ og)
{
    __shared__ uint4 sKt4[2][64*8];   // Kt[m][d-octet g^(m&7)]   2 x 8 KiB
    __shared__ uint4 sVt4[2][64*8];   // Vt[d][m-octet g^(d&7)]   2 x 8 KiB

    const int t    = threadIdx.x;
    const int lane = t & 63;
    const int wv   = t >> 6;
    const int col  = lane & 31;
    const int h    = lane >> 5;

    const int bi   = blockIdx.x;
    const int s    = bi >> 3;
    const int head = (bi & 7)*32 + (s >> 2);   // XCD-affine: bi&7 == XCD id
    const int qt   = s & 3;
    const int b    = bi & 7;

    const float* qh = qg + (size_t)head*32768;
    const float* kh = kg + (size_t)head*32768;
    const float* vh = vg + (size_t)head*32768;
    const int*   mrow = mg + (size_t)b*262144 + (size_t)(qt*128 + wv*32 + col)*512;
    float*       oh = og + (size_t)head*32768;

    // ---- persistent Q B-fragments, pre-scaled by 0.125*log2e ----
    Frag4 qf[4];
    {
        const float* qr = qh + (size_t)(qt*128 + wv*32 + col)*64 + h*8;
        #pragma unroll
        for (int kt=0; kt<4; ++kt){
            float4 x0 = *(const float4*)(qr + kt*16);
            float4 x1 = *(const float4*)(qr + kt*16 + 4);
            qf[kt].u[0] = pk_bf16(x0.x*SCL, x0.y*SCL);
            qf[kt].u[1] = pk_bf16(x0.z*SCL, x0.w*SCL);
            qf[kt].u[2] = pk_bf16(x1.x*SCL, x1.y*SCL);
            qf[kt].u[3] = pk_bf16(x1.z*SCL, x1.w*SCL);
        }
    }

    f32x16 o0, o1;
    #pragma unroll
    for (int i=0;i<16;++i){ o0[i]=0.f; o1[i]=0.f; }
    float lsum = 0.f;

    // ---- prologue: stage chunk 0 into buffer 0 ----
    {
        float nk[2][8], nv[2][8];
        #pragma unroll
        for (int gi=0; gi<2; ++gi){
            const int g = wv + gi*4;
            const float* kp = kh + (size_t)(g*8)*512 + lane;
            const float* vp = vh + (size_t)(g*8)*64 + lane;
            #pragma unroll
            for (int dd=0; dd<8; ++dd){
                nk[gi][dd] = kp[(size_t)dd*512];
                nv[gi][dd] = vp[(size_t)dd*64];
            }
        }
        #pragma unroll
        for (int gi=0; gi<2; ++gi){
            const int g = wv + gi*4;
            Frag4 wk, wvv;
            #pragma unroll
            for (int j=0; j<4; ++j){
                wk.u[j]  = pk_bf16(nk[gi][2*j], nk[gi][2*j+1]);
                wvv.u[j] = pk_bf16(nv[gi][2*j], nv[gi][2*j+1]);
            }
            sKt4[0][lane*8 + (g ^ (lane&7))] = wk.x;
            sVt4[0][lane*8 + (g ^ (lane&7))] = wvv.x;
        }
    }
    __syncthreads();

    #pragma unroll
    for (int kb=0; kb<8; ++kb){
        const int cb = kb & 1;
        const int nb = cb ^ 1;
        const bool pre = (kb < 7);

        // -- prefetch next K chunk (f32 -> regs), issued before any compute
        float nk[2][8];
        if (pre){
            #pragma unroll
            for (int gi=0; gi<2; ++gi){
                const int g = wv + gi*4;
                const float* kp = kh + (size_t)(g*8)*512 + (kb+1)*64 + lane;
                #pragma unroll
                for (int dd=0; dd<8; ++dd) nk[gi][dd] = kp[(size_t)dd*512];
            }
        }
        // -- mask for mt=0, issued ahead of GEMM1
        int4 m0[4];
        #pragma unroll
        for (int rg=0; rg<4; ++rg)
            m0[rg] = *(const int4*)(mrow + kb*64 + rg*8 + h*4);

        // ================= mt = 0 =================
        f32x16 sc;
        #pragma unroll
        for (int i=0;i<16;++i) sc[i]=0.f;
        #pragma unroll
        for (int kt=0; kt<4; ++kt){
            const int r = col;                     // mt*32 + col, mt=0
            Frag4 a; a.x = sKt4[cb][r*8 + ((kt*2+h) ^ (r&7))];
            sc = __builtin_amdgcn_mfma_f32_32x32x16_bf16(a.v, qf[kt].v, sc, 0, 0, 0);
        }
        // -- mask for mt=1 + V prefetch: issue now, consumed later
        int4 m1[4];
        #pragma unroll
        for (int rg=0; rg<4; ++rg)
            m1[rg] = *(const int4*)(mrow + kb*64 + 32 + rg*8 + h*4);
        float nv[2][8];
        if (pre){
            #pragma unroll
            for (int gi=0; gi<2; ++gi){
                const int g = wv + gi*4;
                const float* vp = vh + (size_t)((kb+1)*64 + g*8)*64 + lane;
                #pragma unroll
                for (int mm=0; mm<8; ++mm) nv[gi][mm] = vp[(size_t)mm*64];
            }
        }
        {
            float p[16];
            #pragma unroll
            for (int rg=0; rg<4; ++rg){
                float e0 = m0[rg].x ? 0.f : fast_exp2(sc[4*rg+0]);
                float e1 = m0[rg].y ? 0.f : fast_exp2(sc[4*rg+1]);
                float e2 = m0[rg].z ? 0.f : fast_exp2(sc[4*rg+2]);
                float e3 = m0[rg].w ? 0.f : fast_exp2(sc[4*rg+3]);
                p[4*rg+0]=e0; p[4*rg+1]=e1; p[4*rg+2]=e2; p[4*rg+3]=e3;
                lsum += (e0+e1)+(e2+e3);
            }
            unsigned pp[8];
            #pragma unroll
            for (int r2=0; r2<8; ++r2) pp[r2] = pk_bf16(p[2*r2], p[2*r2+1]);
            #pragma unroll
            for (int c=0; c<2; ++c){
                unsigned keep0 = h ? pp[4*c+2] : pp[4*c+0];
                unsigned keep1 = h ? pp[4*c+3] : pp[4*c+1];
                unsigned give0 = h ? pp[4*c+0] : pp[4*c+2];
                unsigned give1 = h ? pp[4*c+1] : pp[4*c+3];
                unsigned got0 = (unsigned)__shfl_xor((int)give0, 32, 64);
                unsigned got1 = (unsigned)__shfl_xor((int)give1, 32, 64);
                Frag4 pa;
                pa.u[0] = h ? got0  : keep0;
                pa.u[1] = h ? got1  : keep1;
                pa.u[2] = h ? keep0 : got0;
                pa.u[3] = h ? keep1 : got1;
                const int gm = c*2 + h;            // mt*4 + c*2 + h, mt=0
                Frag4 b0; b0.x = sVt4[cb][col*8      + (gm ^ (col&7))];
                o0 = __builtin_amdgcn_mfma_f32_32x32x16_bf16(pa.v, b0.v, o0, 0, 0, 0);
                Frag4 b1; b1.x = sVt4[cb][(32+col)*8 + (gm ^ ((32+col)&7))];
                o1 = __builtin_amdgcn_mfma_f32_32x32x16_bf16(pa.v, b1.v, o1, 0, 0, 0);
            }
        }
        // -- pack next-K now (frees the f32 regs), writes happen after mt1
        Frag4 wk[2];
        if (pre){
            #pragma unroll
            for (int gi=0; gi<2; ++gi)
                #pragma unroll
                for (int j=0; j<4; ++j)
                    wk[gi].u[j] = pk_bf16(nk[gi][2*j], nk[gi][2*j+1]);
        }

        // ================= mt = 1 =================
        #pragma unroll
        for (int i=0;i<16;++i) sc[i]=0.f;
        #pragma unroll
        for (int kt=0; kt<4; ++kt){
            const int r = 32 + col;
            Frag4 a; a.x = sKt4[cb][r*8 + ((kt*2+h) ^ (r&7))];
            sc = __builtin_amdgcn_mfma_f32_32x32x16_bf16(a.v, qf[kt].v, sc, 0, 0, 0);
        }
        {
            float p[16];
            #pragma unroll
            for (int rg=0; rg<4; ++rg){
                float e0 = m1[rg].x ? 0.f : fast_exp2(sc[4*rg+0]);
                float e1 = m1[rg].y ? 0.f : fast_exp2(sc[4*rg+1]);
                float e2 = m1[rg].z ? 0.f : fast_exp2(sc[4*rg+2]);
                float e3 = m1[rg].w ? 0.f : fast_exp2(sc[4*rg+3]);
                p[4*rg+0]=e0; p[4*rg+1]=e1; p[4*rg+2]=e2; p[4*rg+3]=e3;
                lsum += (e0+e1)+(e2+e3);
            }
            unsigned pp[8];
            #pragma unroll
            for (int r2=0; r2<8; ++r2) pp[r2] = pk_bf16(p[2*r2], p[2*r2+1]);
            #pragma unroll
            for (int c=0; c<2; ++c){
                unsigned keep0 = h ? pp[4*c+2] : pp[4*c+0];
                unsigned keep1 = h ? pp[4*c+3] : pp[4*c+1];
                unsigned give0 = h ? pp[4*c+0] : pp[4*c+2];
                unsigned give1 = h ? pp[4*c+1] : pp[4*c+3];
                unsigned got0 = (unsigned)__shfl_xor((int)give0, 32, 64);
                unsigned got1 = (unsigned)__shfl_xor((int)give1, 32, 64);
                Frag4 pa;
                pa.u[0] = h ? got0  : keep0;
                pa.u[1] = h ? got1  : keep1;
                pa.u[2] = h ? keep0 : got0;
                pa.u[3] = h ? keep1 : got1;
                const int gm = 4 + c*2 + h;        // mt=1
                Frag4 b0; b0.x = sVt4[cb][col*8      + (gm ^ (col&7))];
                o0 = __builtin_amdgcn_mfma_f32_32x32x16_bf16(pa.v, b0.v, o0, 0, 0, 0);
                Frag4 b1; b1.x = sVt4[cb][(32+col)*8 + (gm ^ ((32+col)&7))];
                o1 = __builtin_amdgcn_mfma_f32_32x32x16_bf16(pa.v, b1.v, o1, 0, 0, 0);
            }
        }

        // -- stage next chunk into the other buffer, then the ONE barrier
        if (pre){
            #pragma unroll
            for (int gi=0; gi<2; ++gi){
                const int g = wv + gi*4;
                Frag4 wvv;
                #pragma unroll
                for (int j=0; j<4; ++j) wvv.u[j] = pk_bf16(nv[gi][2*j], nv[gi][2*j+1]);
                sKt4[nb][lane*8 + (g ^ (lane&7))] = wk[gi].x;
                sVt4[nb][lane*8 + (g ^ (lane&7))] = wvv.x;
            }
            __syncthreads();
        }
    }

    // ---- normalize + direct coalesced stores ----
    lsum += __shfl_xor(lsum, 32, 64);
    const float inv = 1.0f / lsum;
    float* ob = oh + (size_t)(qt*128 + wv*32)*64;
    #pragma unroll
    for (int r=0; r<16; ++r){
        const int qq = (r&3) + 8*(r>>2) + 4*h;
        const float iv = __shfl(inv, qq, 64);
        ob[(size_t)qq*64 + col]      = o0[r]*iv;
        ob[(size_t)qq*64 + 32 + col] = o1[r]*iv;
    }
}

extern "C" void kernel_launch(void* const* d_in, const int* in_sizes, int n_in,
                              void* d_out, int out_size, void* d_ws, size_t ws_size,
                              hipStream_t stream) {
    (void)in_sizes; (void)n_in; (void)d_ws; (void)ws_size; (void)out_size;
    const float* q = (const float*)d_in[0];
    const float* k = (const float*)d_in[1];
    const float* v = (const float*)d_in[2];
    const int*   m = (const int*)d_in[3];
    attn_fused<<<dim3(1024), dim3(256), 0, stream>>>(q, k, v, m, (float*)d_out);
}

// Round 4
// 326.181 us; speedup vs baseline: 1.0040x; 1.0040x over previous
//
#include <hip/hip_runtime.h>

// Fused SDPA, MI355X gfx950. G=32, H=8, L=512, D=64.
// q:(G,H,L,D) f32, k:(G,H,D,L) f32, v:(G,H,L,D) f32, mask:(8,L,L) int
// (nonzero = masked), out:(G,H,L,D) f32.
//
// Round 4: identical pipelined structure to round 3 (double-buffered LDS,
// register prefetch of chunk kb+1, one barrier/iter) but with
// __launch_bounds__(256,3): VGPR cap 170 instead of 128. Round 3's peak live
// set (~150 VGPRs: o-accum 32 + qf 16 + sc 16 + int4 masks 32 + prefetch 40)
// exceeded the 128 cap -> compiler spilled every pipeline register to scratch
// (WRITE_SIZE 34.8->233 MB was the smoking gun). 3 blocks/CU instead of 4;
// the pipeline, not TLP, hides load latency.

typedef __attribute__((ext_vector_type(8)))  short bf16x8;
typedef __attribute__((ext_vector_type(16))) float f32x16;

union Frag4 { uint4 x; unsigned u[4]; bf16x8 v; };

// pack two f32 -> packed bf16 pair (a -> low, b -> high), round-half-up
__device__ __forceinline__ unsigned pk_bf16(float a, float b){
    unsigned ua = __builtin_bit_cast(unsigned, a) + 0x8000u;
    unsigned ub = __builtin_bit_cast(unsigned, b) + 0x8000u;
    return __builtin_amdgcn_perm(ub, ua, 0x07060302u);
}

__device__ __forceinline__ float fast_exp2(float x){
#if __has_builtin(__builtin_amdgcn_exp2f)
    return __builtin_amdgcn_exp2f(x);
#else
    return exp2f(x);
#endif
}

#define SCL 0.1803368801111204f   // 0.125 * log2(e): GEMM1 output is exp2-ready

__global__ __launch_bounds__(256, 3)
void attn_fused(const float* __restrict__ qg, const float* __restrict__ kg,
                const float* __restrict__ vg, const int* __restrict__ mg,
                float* __restrict__ og)
{
    __shared__ uint4 sKt4[2][64*8];   // Kt[m][d-octet g^(m&7)]   2 x 8 KiB
    __shared__ uint4 sVt4[2][64*8];   // Vt[d][m-octet g^(d&7)]   2 x 8 KiB

    const int t    = threadIdx.x;
    const int lane = t & 63;
    const int wv   = t >> 6;
    const int col  = lane & 31;
    const int h    = lane >> 5;

    const int bi   = blockIdx.x;
    const int s    = bi >> 3;
    const int head = (bi & 7)*32 + (s >> 2);   // XCD-affine: bi&7 == XCD id
    const int qt   = s & 3;
    const int b    = bi & 7;

    const float* qh = qg + (size_t)head*32768;
    const float* kh = kg + (size_t)head*32768;
    const float* vh = vg + (size_t)head*32768;
    const int*   mrow = mg + (size_t)b*262144 + (size_t)(qt*128 + wv*32 + col)*512;
    float*       oh = og + (size_t)head*32768;

    // ---- persistent Q B-fragments, pre-scaled by 0.125*log2e ----
    Frag4 qf[4];
    {
        const float* qr = qh + (size_t)(qt*128 + wv*32 + col)*64 + h*8;
        #pragma unroll
        for (int kt=0; kt<4; ++kt){
            float4 x0 = *(const float4*)(qr + kt*16);
            float4 x1 = *(const float4*)(qr + kt*16 + 4);
            qf[kt].u[0] = pk_bf16(x0.x*SCL, x0.y*SCL);
            qf[kt].u[1] = pk_bf16(x0.z*SCL, x0.w*SCL);
            qf[kt].u[2] = pk_bf16(x1.x*SCL, x1.y*SCL);
            qf[kt].u[3] = pk_bf16(x1.z*SCL, x1.w*SCL);
        }
    }

    f32x16 o0, o1;
    #pragma unroll
    for (int i=0;i<16;++i){ o0[i]=0.f; o1[i]=0.f; }
    float lsum = 0.f;

    // ---- prologue: stage chunk 0 into buffer 0 ----
    {
        float nk[2][8], nv[2][8];
        #pragma unroll
        for (int gi=0; gi<2; ++gi){
            const int g = wv + gi*4;
            const float* kp = kh + (size_t)(g*8)*512 + lane;
            const float* vp = vh + (size_t)(g*8)*64 + lane;
            #pragma unroll
            for (int dd=0; dd<8; ++dd){
                nk[gi][dd] = kp[(size_t)dd*512];
                nv[gi][dd] = vp[(size_t)dd*64];
            }
        }
        #pragma unroll
        for (int gi=0; gi<2; ++gi){
            const int g = wv + gi*4;
            Frag4 wk, wvv;
            #pragma unroll
            for (int j=0; j<4; ++j){
                wk.u[j]  = pk_bf16(nk[gi][2*j], nk[gi][2*j+1]);
                wvv.u[j] = pk_bf16(nv[gi][2*j], nv[gi][2*j+1]);
            }
            sKt4[0][lane*8 + (g ^ (lane&7))] = wk.x;
            sVt4[0][lane*8 + (g ^ (lane&7))] = wvv.x;
        }
    }
    __syncthreads();

    #pragma unroll
    for (int kb=0; kb<8; ++kb){
        const int cb = kb & 1;
        const int nb = cb ^ 1;
        const bool pre = (kb < 7);

        // -- prefetch next K chunk (f32 -> regs), issued before any compute
        float nk[2][8];
        if (pre){
            #pragma unroll
            for (int gi=0; gi<2; ++gi){
                const int g = wv + gi*4;
                const float* kp = kh + (size_t)(g*8)*512 + (kb+1)*64 + lane;
                #pragma unroll
                for (int dd=0; dd<8; ++dd) nk[gi][dd] = kp[(size_t)dd*512];
            }
        }
        // -- mask for mt=0, issued ahead of GEMM1
        int4 m0[4];
        #pragma unroll
        for (int rg=0; rg<4; ++rg)
            m0[rg] = *(const int4*)(mrow + kb*64 + rg*8 + h*4);

        // ================= mt = 0 =================
        f32x16 sc;
        #pragma unroll
        for (int i=0;i<16;++i) sc[i]=0.f;
        #pragma unroll
        for (int kt=0; kt<4; ++kt){
            const int r = col;                     // mt*32 + col, mt=0
            Frag4 a; a.x = sKt4[cb][r*8 + ((kt*2+h) ^ (r&7))];
            sc = __builtin_amdgcn_mfma_f32_32x32x16_bf16(a.v, qf[kt].v, sc, 0, 0, 0);
        }
        // -- mask for mt=1 + V prefetch: issue now, consumed later
        int4 m1[4];
        #pragma unroll
        for (int rg=0; rg<4; ++rg)
            m1[rg] = *(const int4*)(mrow + kb*64 + 32 + rg*8 + h*4);
        float nv[2][8];
        if (pre){
            #pragma unroll
            for (int gi=0; gi<2; ++gi){
                const int g = wv + gi*4;
                const float* vp = vh + (size_t)((kb+1)*64 + g*8)*64 + lane;
                #pragma unroll
                for (int mm=0; mm<8; ++mm) nv[gi][mm] = vp[(size_t)mm*64];
            }
        }
        {
            float p[16];
            #pragma unroll
            for (int rg=0; rg<4; ++rg){
                float e0 = m0[rg].x ? 0.f : fast_exp2(sc[4*rg+0]);
                float e1 = m0[rg].y ? 0.f : fast_exp2(sc[4*rg+1]);
                float e2 = m0[rg].z ? 0.f : fast_exp2(sc[4*rg+2]);
                float e3 = m0[rg].w ? 0.f : fast_exp2(sc[4*rg+3]);
                p[4*rg+0]=e0; p[4*rg+1]=e1; p[4*rg+2]=e2; p[4*rg+3]=e3;
                lsum += (e0+e1)+(e2+e3);
            }
            unsigned pp[8];
            #pragma unroll
            for (int r2=0; r2<8; ++r2) pp[r2] = pk_bf16(p[2*r2], p[2*r2+1]);
            #pragma unroll
            for (int c=0; c<2; ++c){
                unsigned keep0 = h ? pp[4*c+2] : pp[4*c+0];
                unsigned keep1 = h ? pp[4*c+3] : pp[4*c+1];
                unsigned give0 = h ? pp[4*c+0] : pp[4*c+2];
                unsigned give1 = h ? pp[4*c+1] : pp[4*c+3];
                unsigned got0 = (unsigned)__shfl_xor((int)give0, 32, 64);
                unsigned got1 = (unsigned)__shfl_xor((int)give1, 32, 64);
                Frag4 pa;
                pa.u[0] = h ? got0  : keep0;
                pa.u[1] = h ? got1  : keep1;
                pa.u[2] = h ? keep0 : got0;
                pa.u[3] = h ? keep1 : got1;
                const int gm = c*2 + h;            // mt*4 + c*2 + h, mt=0
                Frag4 b0; b0.x = sVt4[cb][col*8      + (gm ^ (col&7))];
                o0 = __builtin_amdgcn_mfma_f32_32x32x16_bf16(pa.v, b0.v, o0, 0, 0, 0);
                Frag4 b1; b1.x = sVt4[cb][(32+col)*8 + (gm ^ ((32+col)&7))];
                o1 = __builtin_amdgcn_mfma_f32_32x32x16_bf16(pa.v, b1.v, o1, 0, 0, 0);
            }
        }
        // -- pack next-K now (frees the f32 regs), writes happen after mt1
        Frag4 wk[2];
        if (pre){
            #pragma unroll
            for (int gi=0; gi<2; ++gi)
                #pragma unroll
                for (int j=0; j<4; ++j)
                    wk[gi].u[j] = pk_bf16(nk[gi][2*j], nk[gi][2*j+1]);
        }

        // ================= mt = 1 =================
        #pragma unroll
        for (int i=0;i<16;++i) sc[i]=0.f;
        #pragma unroll
        for (int kt=0; kt<4; ++kt){
            const int r = 32 + col;
            Frag4 a; a.x = sKt4[cb][r*8 + ((kt*2+h) ^ (r&7))];
            sc = __builtin_amdgcn_mfma_f32_32x32x16_bf16(a.v, qf[kt].v, sc, 0, 0, 0);
        }
        {
            float p[16];
            #pragma unroll
            for (int rg=0; rg<4; ++rg){
                float e0 = m1[rg].x ? 0.f : fast_exp2(sc[4*rg+0]);
                float e1 = m1[rg].y ? 0.f : fast_exp2(sc[4*rg+1]);
                float e2 = m1[rg].z ? 0.f : fast_exp2(sc[4*rg+2]);
                float e3 = m1[rg].w ? 0.f : fast_exp2(sc[4*rg+3]);
                p[4*rg+0]=e0; p[4*rg+1]=e1; p[4*rg+2]=e2; p[4*rg+3]=e3;
                lsum += (e0+e1)+(e2+e3);
            }
            unsigned pp[8];
            #pragma unroll
            for (int r2=0; r2<8; ++r2) pp[r2] = pk_bf16(p[2*r2], p[2*r2+1]);
            #pragma unroll
            for (int c=0; c<2; ++c){
                unsigned keep0 = h ? pp[4*c+2] : pp[4*c+0];
                unsigned keep1 = h ? pp[4*c+3] : pp[4*c+1];
                unsigned give0 = h ? pp[4*c+0] : pp[4*c+2];
                unsigned give1 = h ? pp[4*c+1] : pp[4*c+3];
                unsigned got0 = (unsigned)__shfl_xor((int)give0, 32, 64);
                unsigned got1 = (unsigned)__shfl_xor((int)give1, 32, 64);
                Frag4 pa;
                pa.u[0] = h ? got0  : keep0;
                pa.u[1] = h ? got1  : keep1;
                pa.u[2] = h ? keep0 : got0;
                pa.u[3] = h ? keep1 : got1;
                const int gm = 4 + c*2 + h;        // mt=1
                Frag4 b0; b0.x = sVt4[cb][col*8      + (gm ^ (col&7))];
                o0 = __builtin_amdgcn_mfma_f32_32x32x16_bf16(pa.v, b0.v, o0, 0, 0, 0);
                Frag4 b1; b1.x = sVt4[cb][(32+col)*8 + (gm ^ ((32+col)&7))];
                o1 = __builtin_amdgcn_mfma_f32_32x32x16_bf16(pa.v, b1.v, o1, 0, 0, 0);
            }
        }

        // -- stage next chunk into the other buffer, then the ONE barrier
        if (pre){
            #pragma unroll
            for (int gi=0; gi<2; ++gi){
                const int g = wv + gi*4;
                Frag4 wvv;
                #pragma unroll
                for (int j=0; j<4; ++j) wvv.u[j] = pk_bf16(nv[gi][2*j], nv[gi][2*j+1]);
                sKt4[nb][lane*8 + (g ^ (lane&7))] = wk[gi].x;
                sVt4[nb][lane*8 + (g ^ (lane&7))] = wvv.x;
            }
            __syncthreads();
        }
    }

    // ---- normalize + direct coalesced stores ----
    lsum += __shfl_xor(lsum, 32, 64);
    const float inv = 1.0f / lsum;
    float* ob = oh + (size_t)(qt*128 + wv*32)*64;
    #pragma unroll
    for (int r=0; r<16; ++r){
        const int qq = (r&3) + 8*(r>>2) + 4*h;
        const float iv = __shfl(inv, qq, 64);
        ob[(size_t)qq*64 + col]      = o0[r]*iv;
        ob[(size_t)qq*64 + 32 + col] = o1[r]*iv;
    }
}

extern "C" void kernel_launch(void* const* d_in, const int* in_sizes, int n_in,
                              void* d_out, int out_size, void* d_ws, size_t ws_size,
                              hipStream_t stream) {
    (void)in_sizes; (void)n_in; (void)d_ws; (void)ws_size; (void)out_size;
    const float* q = (const float*)d_in[0];
    const float* k = (const float*)d_in[1];
    const float* v = (const float*)d_in[2];
    const int*   m = (const int*)d_in[3];
    attn_fused<<<dim3(1024), dim3(256), 0, stream>>>(q, k, v, m, (float*)d_out);
}

// Round 5
// 312.512 us; speedup vs baseline: 1.0479x; 1.0437x over previous
//
#include <hip/hip_runtime.h>

// Fused SDPA, MI355X gfx950. G=32, H=8, L=512, D=64.
// q:(G,H,L,D) f32, k:(G,H,D,L) f32, v:(G,H,L,D) f32, mask:(8,L,L) int
// (nonzero = masked), out:(G,H,L,D) f32.
//
// Round 5: pipeline with a pinned live set.
//  - #pragma unroll 1 on the kb loop (R3/R4 full unroll let the scheduler
//    hoist prefetches across iterations -> wholesale spill, 160+ MB scratch).
//  - mask prepass: one wave __ballot's 64 mask ints -> uint64 bitmask in d_ws
//    (256 KB). Per-chunk mask state in the main loop = 2 VGPRs, 1 load.
//  - staggered register prefetch: K f32 at top (packed after mt0), V f32
//    mid (packed after mt1), one barrier/iter, double LDS buffers.
//  - peak live ~120 VGPR -> __launch_bounds__(256,4), 4 blocks/CU, no tail.

typedef __attribute__((ext_vector_type(8)))  short bf16x8;
typedef __attribute__((ext_vector_type(16))) float f32x16;

union Frag4 { uint4 x; unsigned u[4]; bf16x8 v; };

__device__ __forceinline__ unsigned pk_bf16(float a, float b){
    unsigned ua = __builtin_bit_cast(unsigned, a) + 0x8000u;
    unsigned ub = __builtin_bit_cast(unsigned, b) + 0x8000u;
    return __builtin_amdgcn_perm(ub, ua, 0x07060302u);
}

__device__ __forceinline__ float fast_exp2(float x){
#if __has_builtin(__builtin_amdgcn_exp2f)
    return __builtin_amdgcn_exp2f(x);
#else
    return exp2f(x);
#endif
}

#define SCL 0.1803368801111204f   // 0.125 * log2(e): GEMM1 output is exp2-ready

// ---- prepass: mask (8,512,512) int -> bitmask (8,512,8) uint64 ----
__global__ __launch_bounds__(256)
void mask_prepass(const int* __restrict__ mg, unsigned long long* __restrict__ bm)
{
    const int gid  = blockIdx.x*256 + threadIdx.x;
    const int wid  = gid >> 6;          // (b*512+row)*8 + chunk
    const int lane = gid & 63;
    const int chunk = wid & 7;
    const int rowb  = wid >> 3;
    const int x = mg[(size_t)rowb*512 + chunk*64 + lane];
    unsigned long long m = __ballot(x != 0);
    if (lane == 0) bm[wid] = m;
}

template<bool USE_BM>
__global__ __launch_bounds__(256, 4)
void attn_fused(const float* __restrict__ qg, const float* __restrict__ kg,
                const float* __restrict__ vg, const int* __restrict__ mg,
                const unsigned long long* __restrict__ bmg,
                float* __restrict__ og)
{
    __shared__ uint4 sKt4[2][64*8];   // Kt[m][d-octet g^(m&7)]  2 x 8 KiB
    __shared__ uint4 sVt4[2][64*8];   // Vt[d][m-octet g^(d&7)]  2 x 8 KiB

    const int t    = threadIdx.x;
    const int lane = t & 63;
    const int wv   = t >> 6;
    const int col  = lane & 31;
    const int h    = lane >> 5;

    const int bi   = blockIdx.x;
    const int s    = bi >> 3;
    const int head = (bi & 7)*32 + (s >> 2);   // XCD-affine: bi&7 == XCD id
    const int qt   = s & 3;
    const int b    = bi & 7;

    const float* qh = qg + (size_t)head*32768;
    const float* kh = kg + (size_t)head*32768;
    const float* vh = vg + (size_t)head*32768;
    float*       oh = og + (size_t)head*32768;

    const int qrl = qt*128 + wv*32 + col;      // this lane's q-row in [0,512)
    const unsigned long long* bmrow = bmg + ((size_t)(b*512) + qrl)*8;
    const int* mrow = mg + (size_t)b*262144 + (size_t)qrl*512;

    // ---- persistent Q B-fragments, pre-scaled by 0.125*log2e ----
    Frag4 qf[4];
    {
        const float* qr = qh + (size_t)qrl*64 + h*8;
        #pragma unroll
        for (int kt=0; kt<4; ++kt){
            float4 x0 = *(const float4*)(qr + kt*16);
            float4 x1 = *(const float4*)(qr + kt*16 + 4);
            qf[kt].u[0] = pk_bf16(x0.x*SCL, x0.y*SCL);
            qf[kt].u[1] = pk_bf16(x0.z*SCL, x0.w*SCL);
            qf[kt].u[2] = pk_bf16(x1.x*SCL, x1.y*SCL);
            qf[kt].u[3] = pk_bf16(x1.z*SCL, x1.w*SCL);
        }
    }

    f32x16 o0, o1;
    #pragma unroll
    for (int i=0;i<16;++i){ o0[i]=0.f; o1[i]=0.f; }
    float lsum = 0.f;

    // ---- prologue: stage chunk 0 into buffer 0; fetch chunk-0 bitmask ----
    unsigned long long bmCur = 0;
    if (USE_BM) bmCur = bmrow[0];
    {
        float nk[2][8], nv[2][8];
        #pragma unroll
        for (int gi=0; gi<2; ++gi){
            const int g = wv + gi*4;
            const float* kp = kh + (size_t)(g*8)*512 + lane;
            const float* vp = vh + (size_t)(g*8)*64 + lane;
            #pragma unroll
            for (int dd=0; dd<8; ++dd){
                nk[gi][dd] = kp[(size_t)dd*512];
                nv[gi][dd] = vp[(size_t)dd*64];
            }
        }
        #pragma unroll
        for (int gi=0; gi<2; ++gi){
            const int g = wv + gi*4;
            Frag4 wk, wvv;
            #pragma unroll
            for (int j=0; j<4; ++j){
                wk.u[j]  = pk_bf16(nk[gi][2*j], nk[gi][2*j+1]);
                wvv.u[j] = pk_bf16(nv[gi][2*j], nv[gi][2*j+1]);
            }
            sKt4[0][lane*8 + (g ^ (lane&7))] = wk.x;
            sVt4[0][lane*8 + (g ^ (lane&7))] = wvv.x;
        }
    }
    __syncthreads();

    int cb = 0;   // current LDS buffer, flips each iteration

    // one 32-key sub-tile: GEMM1 -> mask+exp -> GEMM2 (lambda keeps code single)
    auto tile = [&](int mt, int kb, unsigned wbits){
        f32x16 sc;
        #pragma unroll
        for (int i=0;i<16;++i) sc[i]=0.f;
        #pragma unroll
        for (int kt=0; kt<4; ++kt){
            const int r = mt*32 + col;
            Frag4 a; a.x = sKt4[cb][r*8 + ((kt*2+h) ^ (r&7))];
            sc = __builtin_amdgcn_mfma_f32_32x32x16_bf16(a.v, qf[kt].v, sc, 0, 0, 0);
        }
        unsigned pp[8];
        #pragma unroll
        for (int rg=0; rg<4; ++rg){
            float e0, e1, e2, e3;
            if (USE_BM){
                const unsigned b4 = wbits >> (8*rg + 4*h);   // bits 0..3 = elems
                e0 = (b4 & 1u) ? 0.f : fast_exp2(sc[4*rg+0]);
                e1 = (b4 & 2u) ? 0.f : fast_exp2(sc[4*rg+1]);
                e2 = (b4 & 4u) ? 0.f : fast_exp2(sc[4*rg+2]);
                e3 = (b4 & 8u) ? 0.f : fast_exp2(sc[4*rg+3]);
            } else {
                int4 mm = *(const int4*)(mrow + kb*64 + mt*32 + rg*8 + h*4);
                e0 = mm.x ? 0.f : fast_exp2(sc[4*rg+0]);
                e1 = mm.y ? 0.f : fast_exp2(sc[4*rg+1]);
                e2 = mm.z ? 0.f : fast_exp2(sc[4*rg+2]);
                e3 = mm.w ? 0.f : fast_exp2(sc[4*rg+3]);
            }
            lsum += (e0+e1)+(e2+e3);
            pp[2*rg+0] = pk_bf16(e0, e1);
            pp[2*rg+1] = pk_bf16(e2, e3);
        }
        #pragma unroll
        for (int c=0; c<2; ++c){
            unsigned keep0 = h ? pp[4*c+2] : pp[4*c+0];
            unsigned keep1 = h ? pp[4*c+3] : pp[4*c+1];
            unsigned give0 = h ? pp[4*c+0] : pp[4*c+2];
            unsigned give1 = h ? pp[4*c+1] : pp[4*c+3];
            unsigned got0 = (unsigned)__shfl_xor((int)give0, 32, 64);
            unsigned got1 = (unsigned)__shfl_xor((int)give1, 32, 64);
            Frag4 pa;
            pa.u[0] = h ? got0  : keep0;
            pa.u[1] = h ? got1  : keep1;
            pa.u[2] = h ? keep0 : got0;
            pa.u[3] = h ? keep1 : got1;
            const int gm = mt*4 + c*2 + h;
            Frag4 b0; b0.x = sVt4[cb][col*8      + (gm ^ (col&7))];
            o0 = __builtin_amdgcn_mfma_f32_32x32x16_bf16(pa.v, b0.v, o0, 0, 0, 0);
            Frag4 b1; b1.x = sVt4[cb][(32+col)*8 + (gm ^ ((32+col)&7))];
            o1 = __builtin_amdgcn_mfma_f32_32x32x16_bf16(pa.v, b1.v, o1, 0, 0, 0);
        }
    };

    #pragma unroll 1
    for (int kb=0; kb<8; ++kb){
        const int nb  = cb ^ 1;
        const bool pre = (kb < 7);

        // -- issue next-K loads (f32, 16 regs) before any compute
        float nk[2][8];
        if (pre){
            #pragma unroll
            for (int gi=0; gi<2; ++gi){
                const int g = wv + gi*4;
                const float* kp = kh + (size_t)(g*8)*512 + (kb+1)*64 + lane;
                #pragma unroll
                for (int dd=0; dd<8; ++dd) nk[gi][dd] = kp[(size_t)dd*512];
            }
        }

        tile(0, kb, (unsigned)bmCur);

        // -- pack K (frees 16 f32 -> 8), then issue V loads + next bitmask
        Frag4 wk[2];
        float nv[2][8];
        unsigned long long bmNext = bmCur;
        if (pre){
            #pragma unroll
            for (int gi=0; gi<2; ++gi)
                #pragma unroll
                for (int j=0; j<4; ++j)
                    wk[gi].u[j] = pk_bf16(nk[gi][2*j], nk[gi][2*j+1]);
            #pragma unroll
            for (int gi=0; gi<2; ++gi){
                const int g = wv + gi*4;
                const float* vp = vh + (size_t)((kb+1)*64 + g*8)*64 + lane;
                #pragma unroll
                for (int mm=0; mm<8; ++mm) nv[gi][mm] = vp[(size_t)mm*64];
            }
            if (USE_BM) bmNext = bmrow[kb+1];
        }

        tile(1, kb, (unsigned)(bmCur >> 32));

        // -- pack V, stage both into the other buffer, one barrier
        if (pre){
            #pragma unroll
            for (int gi=0; gi<2; ++gi){
                const int g = wv + gi*4;
                Frag4 wvv;
                #pragma unroll
                for (int j=0; j<4; ++j) wvv.u[j] = pk_bf16(nv[gi][2*j], nv[gi][2*j+1]);
                sKt4[nb][lane*8 + (g ^ (lane&7))] = wk[gi].x;
                sVt4[nb][lane*8 + (g ^ (lane&7))] = wvv.x;
            }
            __syncthreads();
        }
        bmCur = bmNext;
        cb = nb;
    }

    // ---- normalize + direct coalesced stores ----
    lsum += __shfl_xor(lsum, 32, 64);
    const float inv = 1.0f / lsum;
    float* ob = oh + (size_t)(qt*128 + wv*32)*64;
    #pragma unroll
    for (int r=0; r<16; ++r){
        const int qq = (r&3) + 8*(r>>2) + 4*h;
        const float iv = __shfl(inv, qq, 64);
        ob[(size_t)qq*64 + col]      = o0[r]*iv;
        ob[(size_t)qq*64 + 32 + col] = o1[r]*iv;
    }
}

extern "C" void kernel_launch(void* const* d_in, const int* in_sizes, int n_in,
                              void* d_out, int out_size, void* d_ws, size_t ws_size,
                              hipStream_t stream) {
    (void)in_sizes; (void)n_in; (void)out_size;
    const float* q = (const float*)d_in[0];
    const float* k = (const float*)d_in[1];
    const float* v = (const float*)d_in[2];
    const int*   m = (const int*)d_in[3];
    const size_t bm_bytes = (size_t)8*512*8*sizeof(unsigned long long); // 256 KB
    if (ws_size >= bm_bytes){
        unsigned long long* bm = (unsigned long long*)d_ws;
        mask_prepass<<<dim3(8192), dim3(256), 0, stream>>>(m, bm);
        attn_fused<true><<<dim3(1024), dim3(256), 0, stream>>>(q, k, v, m, bm, (float*)d_out);
    } else {
        attn_fused<false><<<dim3(1024), dim3(256), 0, stream>>>(q, k, v, m, nullptr, (float*)d_out);
    }
}